// Round 1
// baseline (966.634 us; speedup 1.0000x reference)
//
#include <hip/hip_runtime.h>
#include <cstdint>

#define NN 8192
#define EE 131072
#define EPAD (EE + NN)   // edges + self loops = 139264
#define FIN 128
#define CH 512           // H*HID = H*OUT
#define NH 8
#define NEG 0.2f

// ---------- CSR build (shared by both batches / layers) ----------

__global__ __launch_bounds__(256) void k_deg(const int* __restrict__ ei, int* __restrict__ deg) {
    int e = blockIdx.x * 256 + threadIdx.x;
    if (e >= EPAD) return;
    int dst = (e < EE) ? ei[EE + e] : (e - EE);
    atomicAdd(&deg[dst], 1);
}

__global__ __launch_bounds__(1024) void k_scan(const int* __restrict__ deg, int* __restrict__ rowptr) {
    __shared__ int part[1024];
    int t = threadIdx.x;
    int loc[8];
    int s = 0;
#pragma unroll
    for (int i = 0; i < 8; i++) { loc[i] = s; s += deg[t * 8 + i]; }
    part[t] = s;
    __syncthreads();
    if (t == 0) {
        int run = 0;
        for (int i = 0; i < 1024; i++) { int tmp = part[i]; part[i] = run; run += tmp; }
        rowptr[NN] = run;
    }
    __syncthreads();
    int base = part[t];
#pragma unroll
    for (int i = 0; i < 8; i++) rowptr[t * 8 + i] = base + loc[i];
}

__global__ __launch_bounds__(256) void k_scatter(const int* __restrict__ ei, const int* __restrict__ rowptr,
                                                 int* __restrict__ cursor, int* __restrict__ ssrc,
                                                 int* __restrict__ seid) {
    int e = blockIdx.x * 256 + threadIdx.x;
    if (e >= EPAD) return;
    int src = (e < EE) ? ei[e] : (e - EE);
    int dst = (e < EE) ? ei[EE + e] : (e - EE);
    int pos = rowptr[dst] + atomicAdd(&cursor[dst], 1);
    ssrc[pos] = src;
    seid[pos] = e;
}

// ---------- GEMM: XL = F @ Wl, XR = F @ Wr  (F: [NN,K], W: [K,512]) ----------

template <int K>
__global__ __launch_bounds__(256) void k_gemm(const float* __restrict__ F,
                                              const float* __restrict__ Wl, const float* __restrict__ Wr,
                                              float* __restrict__ XL, float* __restrict__ XR) {
    __shared__ float lf[8][K];
    int t = threadIdx.x;
    int r0 = blockIdx.x * 8;
    for (int idx = t; idx < 8 * K; idx += 256)
        lf[idx / K][idx % K] = F[(size_t)(r0 + idx / K) * K + (idx % K)];
    __syncthreads();
    float aL0[8] = {0}, aL1[8] = {0}, aR0[8] = {0}, aR1[8] = {0};
    for (int k = 0; k < K; k++) {
        float wl0 = Wl[k * CH + t], wl1 = Wl[k * CH + t + 256];
        float wr0 = Wr[k * CH + t], wr1 = Wr[k * CH + t + 256];
#pragma unroll
        for (int r = 0; r < 8; r++) {
            float f = lf[r][k];
            aL0[r] += f * wl0; aL1[r] += f * wl1;
            aR0[r] += f * wr0; aR1[r] += f * wr1;
        }
    }
#pragma unroll
    for (int r = 0; r < 8; r++) {
        size_t row = (size_t)(r0 + r) * CH;
        XL[row + t] = aL0[r]; XL[row + t + 256] = aL1[r];
        XR[row + t] = aR0[r]; XR[row + t + 256] = aR1[r];
    }
}

// ---------- per-edge attention logits: LOG[e][h] = sum_c lrelu(xl[src]+xr[dst]) * att[h][c] ----------

__global__ __launch_bounds__(256) void k_logit(const float* __restrict__ XL, const float* __restrict__ XR,
                                               const int* __restrict__ ei, const float* __restrict__ att,
                                               float* __restrict__ LOG) {
    int l = threadIdx.x & 63;
    int e = blockIdx.x * 4 + (threadIdx.x >> 6);
    if (e >= EPAD) return;
    int src = (e < EE) ? ei[e] : (e - EE);
    int dst = (e < EE) ? ei[EE + e] : (e - EE);
    const float* pl = XL + (size_t)src * CH;
    const float* pr = XR + (size_t)dst * CH;
#pragma unroll
    for (int r = 0; r < 8; r++) {
        float v = pl[r * 64 + l] + pr[r * 64 + l];
        v = (v > 0.f) ? v : NEG * v;
        v *= att[r * 64 + l];
#pragma unroll
        for (int off = 32; off; off >>= 1) v += __shfl_xor(v, off);
        if (l == r) LOG[(size_t)e * NH + r] = v;  // lane r writes head r
    }
}

// ---------- per-node softmax + aggregation (one wave per node; CSR order) ----------

__global__ __launch_bounds__(64) void k_node(const float* __restrict__ XL, const float* __restrict__ LOG,
                                             const int* __restrict__ rowptr, const int* __restrict__ ssrc,
                                             const int* __restrict__ seid, const float* __restrict__ bias,
                                             float* __restrict__ OUT, int do_elu) {
    int n = blockIdx.x;
    int l = threadIdx.x;
    int beg = rowptr[n], end = rowptr[n + 1];
    int h = l & 7, slot = l >> 3;
    // phase 1: per-head max over incoming edges
    float m = -1e30f;
    for (int i = beg + slot; i < end; i += 8) m = fmaxf(m, LOG[(size_t)seid[i] * NH + h]);
#pragma unroll
    for (int off = 8; off < 64; off <<= 1) m = fmaxf(m, __shfl_xor(m, off));
    // phase 2: per-head denominator
    float s = 0.f;
    for (int i = beg + slot; i < end; i += 8) s += __expf(LOG[(size_t)seid[i] * NH + h] - m);
#pragma unroll
    for (int off = 8; off < 64; off <<= 1) s += __shfl_xor(s, off);
    float inv = 1.f / s;
    // phase 3: weighted aggregation; lane l owns channel c=l of each head r
    float acc[8] = {0, 0, 0, 0, 0, 0, 0, 0};
    for (int i = beg; i < end; i++) {
        int eid = seid[i], src = ssrc[i];
        float p = __expf(LOG[(size_t)eid * NH + h] - m) * inv;  // lanes 0..7 hold heads 0..7
        const float* pl = XL + (size_t)src * CH;
#pragma unroll
        for (int r = 0; r < 8; r++) acc[r] += __shfl(p, r) * pl[r * 64 + l];
    }
    size_t base = (size_t)n * CH;
#pragma unroll
    for (int r = 0; r < 8; r++) {
        float v = acc[r] + bias[r * 64 + l];
        if (do_elu) v = (v > 0.f) ? v : (__expf(v) - 1.f);
        OUT[base + r * 64 + l] = v;
    }
}

// ---------- host ----------

extern "C" void kernel_launch(void* const* d_in, const int* in_sizes, int n_in,
                              void* d_out, int out_size, void* d_ws, size_t ws_size,
                              hipStream_t stream) {
    const float* x    = (const float*)d_in[0];
    const int*   ei   = (const int*)d_in[1];
    const float* W1l  = (const float*)d_in[2];
    const float* W1r  = (const float*)d_in[3];
    const float* att1 = (const float*)d_in[4];
    const float* b1   = (const float*)d_in[5];
    const float* W2l  = (const float*)d_in[6];
    const float* W2r  = (const float*)d_in[7];
    const float* att2 = (const float*)d_in[8];
    const float* b2   = (const float*)d_in[9];
    float* out = (float*)d_out;

    char* ws = (char*)d_ws;
    int* rowptr = (int*)ws;                 // NN+1
    int* cursor = rowptr + NN + 1;          // NN
    int* deg    = cursor + NN;              // NN
    int* ssrc   = deg + NN;                 // EPAD
    int* seid   = ssrc + EPAD;              // EPAD
    float* XL = (float*)(((uintptr_t)(seid + EPAD) + 255) & ~(uintptr_t)255);
    float* XR  = XL + (size_t)NN * CH;
    float* H1  = XR + (size_t)NN * CH;
    float* LOG = H1 + (size_t)NN * CH;      // EPAD * NH

    // zero cursor + deg (contiguous)
    hipMemsetAsync(cursor, 0, (size_t)2 * NN * sizeof(int), stream);
    k_deg<<<(EPAD + 255) / 256, 256, 0, stream>>>(ei, deg);
    k_scan<<<1, 1024, 0, stream>>>(deg, rowptr);
    k_scatter<<<(EPAD + 255) / 256, 256, 0, stream>>>(ei, rowptr, cursor, ssrc, seid);

    for (int b = 0; b < 2; b++) {
        const float* f = x + (size_t)b * NN * FIN;
        // layer 1
        k_gemm<FIN><<<NN / 8, 256, 0, stream>>>(f, W1l, W1r, XL, XR);
        k_logit<<<(EPAD + 3) / 4, 256, 0, stream>>>(XL, XR, ei, att1, LOG);
        k_node<<<NN, 64, 0, stream>>>(XL, LOG, rowptr, ssrc, seid, b1, H1, 0);
        // layer 2
        k_gemm<CH><<<NN / 8, 256, 0, stream>>>(H1, W2l, W2r, XL, XR);
        k_logit<<<(EPAD + 3) / 4, 256, 0, stream>>>(XL, XR, ei, att2, LOG);
        k_node<<<NN, 64, 0, stream>>>(XL, LOG, rowptr, ssrc, seid, b2,
                                      out + (size_t)b * NN * CH, 1);
    }
}

// Round 2
// 667.446 us; speedup vs baseline: 1.4483x; 1.4483x over previous
//
#include <hip/hip_runtime.h>
#include <cstdint>

#define NN 8192
#define EE 131072
#define EPAD (EE + NN)   // edges + self loops = 139264
#define FIN 128
#define CH 512           // H*HID = H*OUT
#define NH 8
#define NEG 0.2f

// ---------- CSR build (shared by both batches / layers) ----------

__global__ __launch_bounds__(256) void k_deg(const int* __restrict__ ei, int* __restrict__ deg) {
    int e = blockIdx.x * 256 + threadIdx.x;
    if (e >= EPAD) return;
    int dst = (e < EE) ? ei[EE + e] : (e - EE);
    atomicAdd(&deg[dst], 1);
}

__global__ __launch_bounds__(1024) void k_scan(const int* __restrict__ deg, int* __restrict__ rowptr) {
    __shared__ int part[1024];
    int t = threadIdx.x;
    int loc[8];
    int s = 0;
#pragma unroll
    for (int i = 0; i < 8; i++) { loc[i] = s; s += deg[t * 8 + i]; }
    part[t] = s;
    __syncthreads();
    if (t == 0) {
        int run = 0;
        for (int i = 0; i < 1024; i++) { int tmp = part[i]; part[i] = run; run += tmp; }
        rowptr[NN] = run;
    }
    __syncthreads();
    int base = part[t];
#pragma unroll
    for (int i = 0; i < 8; i++) rowptr[t * 8 + i] = base + loc[i];
}

__global__ __launch_bounds__(256) void k_scatter(const int* __restrict__ ei, const int* __restrict__ rowptr,
                                                 int* __restrict__ cursor, int* __restrict__ ssrc) {
    int e = blockIdx.x * 256 + threadIdx.x;
    if (e >= EPAD) return;
    int src = (e < EE) ? ei[e] : (e - EE);
    int dst = (e < EE) ? ei[EE + e] : (e - EE);
    int pos = rowptr[dst] + atomicAdd(&cursor[dst], 1);
    ssrc[pos] = src;
}

// ---------- GEMM: XL = F @ Wl, XR = F @ Wr  (F: [NN,K], W: [K,512]) ----------

template <int K>
__global__ __launch_bounds__(256) void k_gemm(const float* __restrict__ F,
                                              const float* __restrict__ Wl, const float* __restrict__ Wr,
                                              float* __restrict__ XL, float* __restrict__ XR) {
    __shared__ float lf[8][K];
    int t = threadIdx.x;
    int r0 = blockIdx.x * 8;
    for (int idx = t; idx < 8 * K; idx += 256)
        lf[idx / K][idx % K] = F[(size_t)(r0 + idx / K) * K + (idx % K)];
    __syncthreads();
    float aL0[8] = {0}, aL1[8] = {0}, aR0[8] = {0}, aR1[8] = {0};
    for (int k = 0; k < K; k++) {
        float wl0 = Wl[k * CH + t], wl1 = Wl[k * CH + t + 256];
        float wr0 = Wr[k * CH + t], wr1 = Wr[k * CH + t + 256];
#pragma unroll
        for (int r = 0; r < 8; r++) {
            float f = lf[r][k];
            aL0[r] += f * wl0; aL1[r] += f * wl1;
            aR0[r] += f * wr0; aR1[r] += f * wr1;
        }
    }
#pragma unroll
    for (int r = 0; r < 8; r++) {
        size_t row = (size_t)(r0 + r) * CH;
        XL[row + t] = aL0[r]; XL[row + t + 256] = aL1[r];
        XR[row + t] = aR0[r]; XR[row + t + 256] = aR1[r];
    }
}

// ---------- fused per-node: logits + online softmax + aggregation ----------
// One wave per node. Lane l owns channel l of every head; head h channels are
// elements h*64+l. After the fold-reduce each lane holds the logit of head
// (l&7), replicated across the eight 8-lane groups.

__global__ __launch_bounds__(256) void k_node2(const float* __restrict__ XL,
                                               const float* __restrict__ XR,
                                               const int* __restrict__ rowptr,
                                               const int* __restrict__ ssrc,
                                               const float* __restrict__ att,
                                               const float* __restrict__ bias,
                                               float* __restrict__ OUT, int do_elu) {
    int n = blockIdx.x * 4 + (threadIdx.x >> 6);
    int l = threadIdx.x & 63;
    int beg = rowptr[n], end = rowptr[n + 1];

    float xr[8], at[8], acc[8];
    const float* pr = XR + (size_t)n * CH;
#pragma unroll
    for (int r = 0; r < 8; r++) {
        xr[r] = pr[r * 64 + l];
        at[r] = att[r * 64 + l];
        acc[r] = 0.f;
    }
    float mh = -1e30f, sh = 0.f;

    // software-pipelined gather of XL[src]
    int src0 = ssrc[beg];
    float nx[8];
    {
        const float* pl = XL + (size_t)src0 * CH;
#pragma unroll
        for (int r = 0; r < 8; r++) nx[r] = pl[r * 64 + l];
    }

    for (int i = beg; i < end; i++) {
        float cur[8];
#pragma unroll
        for (int r = 0; r < 8; r++) cur[r] = nx[r];
        if (i + 1 < end) {
            int s2 = ssrc[i + 1];
            const float* p2 = XL + (size_t)s2 * CH;
#pragma unroll
            for (int r = 0; r < 8; r++) nx[r] = p2[r * 64 + l];
        }
        // per-(head,channel) attention input
        float v[8];
#pragma unroll
        for (int r = 0; r < 8; r++) {
            float t = cur[r] + xr[r];
            t = (t > 0.f) ? t : NEG * t;
            v[r] = t * at[r];
        }
        // fold-reduce: 3 steps align head bit with lane bit (7 shuffles)
        {
            int b = l & 1;
            float k0 = b ? v[1] : v[0], s0 = b ? v[0] : v[1];
            float k1 = b ? v[3] : v[2], s1 = b ? v[2] : v[3];
            float k2 = b ? v[5] : v[4], s2 = b ? v[4] : v[5];
            float k3 = b ? v[7] : v[6], s3 = b ? v[6] : v[7];
            v[0] = k0 + __shfl_xor(s0, 1);
            v[1] = k1 + __shfl_xor(s1, 1);
            v[2] = k2 + __shfl_xor(s2, 1);
            v[3] = k3 + __shfl_xor(s3, 1);
        }
        {
            int b = (l >> 1) & 1;
            float k0 = b ? v[1] : v[0], s0 = b ? v[0] : v[1];
            float k1 = b ? v[3] : v[2], s1 = b ? v[2] : v[3];
            v[0] = k0 + __shfl_xor(s0, 2);
            v[1] = k1 + __shfl_xor(s1, 2);
        }
        {
            int b = (l >> 2) & 1;
            float k0 = b ? v[1] : v[0], s0 = b ? v[0] : v[1];
            v[0] = k0 + __shfl_xor(s0, 4);
        }
        float lg = v[0];
        lg += __shfl_xor(lg, 8);
        lg += __shfl_xor(lg, 16);
        lg += __shfl_xor(lg, 32);
        // online softmax update; defer-rescale fast path (wave-uniform)
        unsigned long long grow = __ballot(lg > mh);
        if (grow == 0ULL) {
            float p = __expf(lg - mh);
            sh += p;
#pragma unroll
            for (int r = 0; r < 8; r++) acc[r] += __shfl(p, r) * cur[r];
        } else {
            float nm = fmaxf(mh, lg);
            float scale = __expf(mh - nm);
            float p = __expf(lg - nm);
            sh = sh * scale + p;
            mh = nm;
#pragma unroll
            for (int r = 0; r < 8; r++) acc[r] = acc[r] * __shfl(scale, r) + __shfl(p, r) * cur[r];
        }
    }
    float inv = 1.f / sh;
    size_t base = (size_t)n * CH;
#pragma unroll
    for (int r = 0; r < 8; r++) {
        float w = acc[r] * __shfl(inv, r) + bias[r * 64 + l];
        if (do_elu) w = (w > 0.f) ? w : (__expf(w) - 1.f);
        OUT[base + r * 64 + l] = w;
    }
}

// ---------- host ----------

extern "C" void kernel_launch(void* const* d_in, const int* in_sizes, int n_in,
                              void* d_out, int out_size, void* d_ws, size_t ws_size,
                              hipStream_t stream) {
    const float* x    = (const float*)d_in[0];
    const int*   ei   = (const int*)d_in[1];
    const float* W1l  = (const float*)d_in[2];
    const float* W1r  = (const float*)d_in[3];
    const float* att1 = (const float*)d_in[4];
    const float* b1   = (const float*)d_in[5];
    const float* W2l  = (const float*)d_in[6];
    const float* W2r  = (const float*)d_in[7];
    const float* att2 = (const float*)d_in[8];
    const float* b2   = (const float*)d_in[9];
    float* out = (float*)d_out;

    char* ws = (char*)d_ws;
    int* rowptr = (int*)ws;                 // NN+1
    int* cursor = rowptr + NN + 1;          // NN
    int* deg    = cursor + NN;              // NN
    int* ssrc   = deg + NN;                 // EPAD
    float* XL = (float*)(((uintptr_t)(ssrc + EPAD) + 255) & ~(uintptr_t)255);
    float* XR  = XL + (size_t)NN * CH;
    float* H1  = XR + (size_t)NN * CH;

    // zero cursor + deg (contiguous)
    hipMemsetAsync(cursor, 0, (size_t)2 * NN * sizeof(int), stream);
    k_deg<<<(EPAD + 255) / 256, 256, 0, stream>>>(ei, deg);
    k_scan<<<1, 1024, 0, stream>>>(deg, rowptr);
    k_scatter<<<(EPAD + 255) / 256, 256, 0, stream>>>(ei, rowptr, cursor, ssrc);

    for (int b = 0; b < 2; b++) {
        const float* f = x + (size_t)b * NN * FIN;
        // layer 1
        k_gemm<FIN><<<NN / 8, 256, 0, stream>>>(f, W1l, W1r, XL, XR);
        k_node2<<<NN / 4, 256, 0, stream>>>(XL, XR, rowptr, ssrc, att1, b1, H1, 0);
        // layer 2
        k_gemm<CH><<<NN / 8, 256, 0, stream>>>(H1, W2l, W2r, XL, XR);
        k_node2<<<NN / 4, 256, 0, stream>>>(XL, XR, rowptr, ssrc, att2, b2,
                                            out + (size_t)b * NN * CH, 1);
    }
}

// Round 3
// 421.065 us; speedup vs baseline: 2.2957x; 1.5851x over previous
//
#include <hip/hip_runtime.h>
#include <cstdint>

#define NN 8192
#define EE 131072
#define EPAD (EE + NN)   // edges + self loops = 139264
#define FIN 128
#define CH 512           // H*HID = H*OUT
#define NH 8
#define NEG 0.2f

typedef __attribute__((ext_vector_type(8))) short short8;
typedef __attribute__((ext_vector_type(4))) float f32x4;

__device__ inline unsigned short bf16rne(float x) {
    unsigned u = __float_as_uint(x);
    unsigned r = (u + 0x7FFFu + ((u >> 16) & 1u)) >> 16;
    return (unsigned short)r;
}
__device__ inline float bf16tof(unsigned short h) {
    return __uint_as_float((unsigned)h << 16);
}
__device__ inline void gload16(const void* g, void* l) {
    __builtin_amdgcn_global_load_lds((const __attribute__((address_space(1))) void*)g,
                                     (__attribute__((address_space(3))) void*)l, 16, 0, 0);
}

// ---------- CSR build ----------

__global__ __launch_bounds__(256) void k_deg(const int* __restrict__ ei, int* __restrict__ deg) {
    int e = blockIdx.x * 256 + threadIdx.x;
    if (e >= EPAD) return;
    int dst = (e < EE) ? ei[EE + e] : (e - EE);
    atomicAdd(&deg[dst], 1);
}

__global__ __launch_bounds__(1024) void k_scan(const int* __restrict__ deg, int* __restrict__ rowptr) {
    __shared__ int part[1024];
    int t = threadIdx.x;
    int loc[8];
    int s = 0;
#pragma unroll
    for (int i = 0; i < 8; i++) { loc[i] = s; s += deg[t * 8 + i]; }
    part[t] = s;
    __syncthreads();
    if (t == 0) {
        int run = 0;
        for (int i = 0; i < 1024; i++) { int tmp = part[i]; part[i] = run; run += tmp; }
        rowptr[NN] = run;
    }
    __syncthreads();
    int base = part[t];
#pragma unroll
    for (int i = 0; i < 8; i++) rowptr[t * 8 + i] = base + loc[i];
}

__global__ __launch_bounds__(256) void k_scatter(const int* __restrict__ ei, const int* __restrict__ rowptr,
                                                 int* __restrict__ cursor, int* __restrict__ ssrc) {
    int e = blockIdx.x * 256 + threadIdx.x;
    if (e >= EPAD) return;
    int src = (e < EE) ? ei[e] : (e - EE);
    int dst = (e < EE) ? ei[EE + e] : (e - EE);
    int pos = rowptr[dst] + atomicAdd(&cursor[dst], 1);
    ssrc[pos] = src;
}

// ---------- hi/lo split conversions ----------

__global__ __launch_bounds__(256) void k_cvt_a(const float* __restrict__ F,
                                               unsigned short* __restrict__ Ah,
                                               unsigned short* __restrict__ Al, int n4) {
    int i = blockIdx.x * 256 + threadIdx.x;
    if (i >= n4) return;
    f32x4 v = ((const f32x4*)F)[i];
#pragma unroll
    for (int c = 0; c < 4; c++) {
        unsigned short h = bf16rne(v[c]);
        Ah[i * 4 + c] = h;
        Al[i * 4 + c] = bf16rne(v[c] - bf16tof(h));
    }
}

// W[K][512] (Wl,Wr) -> Wt[n=1024][K] hi/lo (transposed, K contiguous)
template <int K>
__global__ __launch_bounds__(256) void k_cvt_w(const float* __restrict__ Wl, const float* __restrict__ Wr,
                                               unsigned short* __restrict__ Wh, unsigned short* __restrict__ Wlo) {
    int idx = blockIdx.x * 256 + threadIdx.x;   // = n*K + k
    int n = idx / K, k = idx % K;
    const float* W = (n < 512) ? Wl : Wr;
    float x = W[k * 512 + (n & 511)];
    unsigned short h = bf16rne(x);
    Wh[idx] = h;
    Wlo[idx] = bf16rne(x - bf16tof(h));
}

// ---------- split-bf16 MFMA GEMM: [8192 x K] @ [K x 1024] -> XL|XR ----------
// 128x128 tile, 4 waves, each wave 64x64 via 4x4 frags of 16x16x32.
// LDS tiles [kh(4)][row(128)][8] bf16; staged via global_load_lds width-16.

template <int K>
__global__ __launch_bounds__(256) void k_gemm_mfma(const unsigned short* __restrict__ Ah,
                                                   const unsigned short* __restrict__ Al,
                                                   const unsigned short* __restrict__ Bh,
                                                   const unsigned short* __restrict__ Bl,
                                                   float* __restrict__ XL, float* __restrict__ XR) {
    __shared__ unsigned short sAh[4][128][8], sAl[4][128][8], sBh[4][128][8], sBl[4][128][8];
    int tid = threadIdx.x;
    int l = tid & 63;
    int w = tid >> 6, wm = w >> 1, wn = w & 1;
    int m0 = blockIdx.x * 128, n0 = blockIdx.y * 128;
    int lr = l & 15, kh = l >> 4;
    f32x4 acc[4][4] = {};

    for (int k0 = 0; k0 < K; k0 += 32) {
#pragma unroll
        for (int g = 0; g < 2; g++) {
            int cell = g * 256 + tid;
            int ckh = cell >> 7, cr = cell & 127;
            int ka = k0 + ckh * 8;
            gload16(Ah + (size_t)(m0 + cr) * K + ka, &sAh[ckh][cr][0]);
            gload16(Al + (size_t)(m0 + cr) * K + ka, &sAl[ckh][cr][0]);
            gload16(Bh + (size_t)(n0 + cr) * K + ka, &sBh[ckh][cr][0]);
            gload16(Bl + (size_t)(n0 + cr) * K + ka, &sBl[ckh][cr][0]);
        }
        __syncthreads();
        short8 fah[4], fal[4], fbh[4], fbl[4];
#pragma unroll
        for (int i = 0; i < 4; i++) {
            fah[i] = *(const short8*)&sAh[kh][wm * 64 + i * 16 + lr][0];
            fal[i] = *(const short8*)&sAl[kh][wm * 64 + i * 16 + lr][0];
            fbh[i] = *(const short8*)&sBh[kh][wn * 64 + i * 16 + lr][0];
            fbl[i] = *(const short8*)&sBl[kh][wn * 64 + i * 16 + lr][0];
        }
#pragma unroll
        for (int i = 0; i < 4; i++)
#pragma unroll
            for (int j = 0; j < 4; j++) {
                acc[i][j] = __builtin_amdgcn_mfma_f32_16x16x32_bf16(fal[i], fbh[j], acc[i][j], 0, 0, 0);
                acc[i][j] = __builtin_amdgcn_mfma_f32_16x16x32_bf16(fah[i], fbl[j], acc[i][j], 0, 0, 0);
                acc[i][j] = __builtin_amdgcn_mfma_f32_16x16x32_bf16(fah[i], fbh[j], acc[i][j], 0, 0, 0);
            }
        __syncthreads();
    }
    // C/D layout: col = lane&15, row = (lane>>4)*4 + q  [m89-verified]
    int colt = n0 + wn * 64;
    float* O = (colt < 512) ? XL : XR;
    int cb = colt & 511;
#pragma unroll
    for (int i = 0; i < 4; i++) {
        int mg = m0 + wm * 64 + i * 16 + kh * 4;
#pragma unroll
        for (int j = 0; j < 4; j++) {
            int cg = cb + j * 16 + lr;
#pragma unroll
            for (int q = 0; q < 4; q++)
                O[(size_t)(mg + q) * CH + cg] = acc[i][j][q];
        }
    }
}

// ---------- fused per-node: logits + online softmax + aggregation ----------

template <int WRITE_BF16>
__global__ __launch_bounds__(256) void k_node2(const float* __restrict__ XL,
                                               const float* __restrict__ XR,
                                               const int* __restrict__ rowptr,
                                               const int* __restrict__ ssrc,
                                               const float* __restrict__ att,
                                               const float* __restrict__ bias,
                                               float* __restrict__ OUT,
                                               unsigned short* __restrict__ OAh,
                                               unsigned short* __restrict__ OAl) {
    int n = blockIdx.x * 4 + (threadIdx.x >> 6);
    int l = threadIdx.x & 63;
    int beg = rowptr[n], end = rowptr[n + 1];

    float xr[8], at[8], acc[8];
    const float* pr = XR + (size_t)n * CH;
#pragma unroll
    for (int r = 0; r < 8; r++) {
        xr[r] = pr[r * 64 + l];
        at[r] = att[r * 64 + l];
        acc[r] = 0.f;
    }
    float mh = -1e30f, sh = 0.f;

    int src0 = ssrc[beg];
    float nx[8];
    {
        const float* pl = XL + (size_t)src0 * CH;
#pragma unroll
        for (int r = 0; r < 8; r++) nx[r] = pl[r * 64 + l];
    }

    for (int i = beg; i < end; i++) {
        float cur[8];
#pragma unroll
        for (int r = 0; r < 8; r++) cur[r] = nx[r];
        if (i + 1 < end) {
            int s2 = ssrc[i + 1];
            const float* p2 = XL + (size_t)s2 * CH;
#pragma unroll
            for (int r = 0; r < 8; r++) nx[r] = p2[r * 64 + l];
        }
        float v[8];
#pragma unroll
        for (int r = 0; r < 8; r++) {
            float t = cur[r] + xr[r];
            t = (t > 0.f) ? t : NEG * t;
            v[r] = t * at[r];
        }
        {
            int b = l & 1;
            float k0 = b ? v[1] : v[0], s0 = b ? v[0] : v[1];
            float k1 = b ? v[3] : v[2], s1 = b ? v[2] : v[3];
            float k2 = b ? v[5] : v[4], s2 = b ? v[4] : v[5];
            float k3 = b ? v[7] : v[6], s3 = b ? v[6] : v[7];
            v[0] = k0 + __shfl_xor(s0, 1);
            v[1] = k1 + __shfl_xor(s1, 1);
            v[2] = k2 + __shfl_xor(s2, 1);
            v[3] = k3 + __shfl_xor(s3, 1);
        }
        {
            int b = (l >> 1) & 1;
            float k0 = b ? v[1] : v[0], s0 = b ? v[0] : v[1];
            float k1 = b ? v[3] : v[2], s1 = b ? v[2] : v[3];
            v[0] = k0 + __shfl_xor(s0, 2);
            v[1] = k1 + __shfl_xor(s1, 2);
        }
        {
            int b = (l >> 2) & 1;
            float k0 = b ? v[1] : v[0], s0 = b ? v[0] : v[1];
            v[0] = k0 + __shfl_xor(s0, 4);
        }
        float lg = v[0];
        lg += __shfl_xor(lg, 8);
        lg += __shfl_xor(lg, 16);
        lg += __shfl_xor(lg, 32);
        unsigned long long grow = __ballot(lg > mh);
        if (grow == 0ULL) {
            float p = __expf(lg - mh);
            sh += p;
#pragma unroll
            for (int r = 0; r < 8; r++) acc[r] += __shfl(p, r) * cur[r];
        } else {
            float nm = fmaxf(mh, lg);
            float scale = __expf(mh - nm);
            float p = __expf(lg - nm);
            sh = sh * scale + p;
            mh = nm;
#pragma unroll
            for (int r = 0; r < 8; r++) acc[r] = acc[r] * __shfl(scale, r) + __shfl(p, r) * cur[r];
        }
    }
    float inv = 1.f / sh;
    size_t base = (size_t)n * CH;
#pragma unroll
    for (int r = 0; r < 8; r++) {
        float wv = acc[r] * __shfl(inv, r) + bias[r * 64 + l];
        if (WRITE_BF16) {
            unsigned short h = bf16rne(wv);
            OAh[base + r * 64 + l] = h;
            OAl[base + r * 64 + l] = bf16rne(wv - bf16tof(h));
        } else {
            wv = (wv > 0.f) ? wv : (__expf(wv) - 1.f);
            OUT[base + r * 64 + l] = wv;
        }
    }
}

// ---------- host ----------

extern "C" void kernel_launch(void* const* d_in, const int* in_sizes, int n_in,
                              void* d_out, int out_size, void* d_ws, size_t ws_size,
                              hipStream_t stream) {
    const float* x    = (const float*)d_in[0];
    const int*   ei   = (const int*)d_in[1];
    const float* W1l  = (const float*)d_in[2];
    const float* W1r  = (const float*)d_in[3];
    const float* att1 = (const float*)d_in[4];
    const float* b1   = (const float*)d_in[5];
    const float* W2l  = (const float*)d_in[6];
    const float* W2r  = (const float*)d_in[7];
    const float* att2 = (const float*)d_in[8];
    const float* b2   = (const float*)d_in[9];
    float* out = (float*)d_out;

    char* ws = (char*)d_ws;
    int* rowptr = (int*)ws;                 // NN+1
    int* cursor = rowptr + NN + 1;          // NN
    int* deg    = cursor + NN;              // NN
    int* ssrc   = deg + NN;                 // EPAD
    float* XL = (float*)(((uintptr_t)(ssrc + EPAD) + 255) & ~(uintptr_t)255);
    float* XR = XL + (size_t)NN * CH;
    unsigned short* A_h = (unsigned short*)(XR + (size_t)NN * CH);  // NN*CH bf16
    unsigned short* A_l = A_h + (size_t)NN * CH;
    unsigned short* W1h = A_l + (size_t)NN * CH;   // 1024*FIN
    unsigned short* W1o = W1h + 1024 * FIN;
    unsigned short* W2h = W1o + 1024 * FIN;        // 1024*CH
    unsigned short* W2o = W2h + 1024 * CH;

    hipMemsetAsync(cursor, 0, (size_t)2 * NN * sizeof(int), stream);
    k_deg<<<(EPAD + 255) / 256, 256, 0, stream>>>(ei, deg);
    k_scan<<<1, 1024, 0, stream>>>(deg, rowptr);
    k_scatter<<<(EPAD + 255) / 256, 256, 0, stream>>>(ei, rowptr, cursor, ssrc);
    k_cvt_w<FIN><<<1024 * FIN / 256, 256, 0, stream>>>(W1l, W1r, W1h, W1o);
    k_cvt_w<CH><<<1024 * CH / 256, 256, 0, stream>>>(W2l, W2r, W2h, W2o);

    for (int b = 0; b < 2; b++) {
        const float* f = x + (size_t)b * NN * FIN;
        k_cvt_a<<<NN * FIN / 4 / 256, 256, 0, stream>>>(f, A_h, A_l, NN * FIN / 4);
        k_gemm_mfma<FIN><<<dim3(NN / 128, 8), 256, 0, stream>>>(A_h, A_l, W1h, W1o, XL, XR);
        k_node2<1><<<NN / 4, 256, 0, stream>>>(XL, XR, rowptr, ssrc, att1, b1, nullptr, A_h, A_l);
        k_gemm_mfma<CH><<<dim3(NN / 128, 8), 256, 0, stream>>>(A_h, A_l, W2h, W2o, XL, XR);
        k_node2<0><<<NN / 4, 256, 0, stream>>>(XL, XR, rowptr, ssrc, att2, b2,
                                               out + (size_t)b * NN * CH, nullptr, nullptr);
    }
}

// Round 4
// 405.922 us; speedup vs baseline: 2.3813x; 1.0373x over previous
//
#include <hip/hip_runtime.h>
#include <cstdint>

#define NN 8192
#define EE 131072
#define EPAD (EE + NN)   // edges + self loops = 139264
#define FIN 128
#define CH 512           // H*HID = H*OUT
#define NH 8
#define NEG 0.2f

typedef __attribute__((ext_vector_type(8))) short short8;
typedef __attribute__((ext_vector_type(4))) float f32x4;

__device__ inline unsigned short bf16rne(float x) {
    unsigned u = __float_as_uint(x);
    unsigned r = (u + 0x7FFFu + ((u >> 16) & 1u)) >> 16;
    return (unsigned short)r;
}
__device__ inline float bf16tof(unsigned short h) {
    return __uint_as_float((unsigned)h << 16);
}
__device__ inline void gload16(const void* g, void* l) {
    __builtin_amdgcn_global_load_lds((const __attribute__((address_space(1))) void*)g,
                                     (__attribute__((address_space(3))) void*)l, 16, 0, 0);
}

// ---------- CSR build ----------

__global__ __launch_bounds__(256) void k_deg(const int* __restrict__ ei, int* __restrict__ deg) {
    int e = blockIdx.x * 256 + threadIdx.x;
    if (e >= EPAD) return;
    int dst = (e < EE) ? ei[EE + e] : (e - EE);
    atomicAdd(&deg[dst], 1);
}

__global__ __launch_bounds__(1024) void k_scan(const int* __restrict__ deg, int* __restrict__ rowptr) {
    __shared__ int part[1024];
    int t = threadIdx.x;
    int loc[8];
    int s = 0;
#pragma unroll
    for (int i = 0; i < 8; i++) { loc[i] = s; s += deg[t * 8 + i]; }
    part[t] = s;
    __syncthreads();
    if (t == 0) {
        int run = 0;
        for (int i = 0; i < 1024; i++) { int tmp = part[i]; part[i] = run; run += tmp; }
        rowptr[NN] = run;
    }
    __syncthreads();
    int base = part[t];
#pragma unroll
    for (int i = 0; i < 8; i++) rowptr[t * 8 + i] = base + loc[i];
}

__global__ __launch_bounds__(256) void k_scatter(const int* __restrict__ ei, const int* __restrict__ rowptr,
                                                 int* __restrict__ cursor, int* __restrict__ ssrc) {
    int e = blockIdx.x * 256 + threadIdx.x;
    if (e >= EPAD) return;
    int src = (e < EE) ? ei[e] : (e - EE);
    int dst = (e < EE) ? ei[EE + e] : (e - EE);
    int pos = rowptr[dst] + atomicAdd(&cursor[dst], 1);
    ssrc[pos] = src;
}

// ---------- conversions ----------

__global__ __launch_bounds__(256) void k_cvt_ah(const float* __restrict__ F,
                                                unsigned short* __restrict__ Ah, int n4) {
    int i = blockIdx.x * 256 + threadIdx.x;
    if (i >= n4) return;
    f32x4 v = ((const f32x4*)F)[i];
#pragma unroll
    for (int c = 0; c < 4; c++) Ah[i * 4 + c] = bf16rne(v[c]);
}

// W[K][512] (Wl,Wr) -> Wt[n=1024][K] hi/lo (transposed, K contiguous)
template <int K>
__global__ __launch_bounds__(256) void k_cvt_w(const float* __restrict__ Wl, const float* __restrict__ Wr,
                                               unsigned short* __restrict__ Wh, unsigned short* __restrict__ Wlo) {
    int idx = blockIdx.x * 256 + threadIdx.x;   // = n*K + k
    int n = idx / K, k = idx % K;
    const float* W = (n < 512) ? Wl : Wr;
    float x = W[k * 512 + (n & 511)];
    unsigned short h = bf16rne(x);
    Wh[idx] = h;
    Wlo[idx] = bf16rne(x - bf16tof(h));
}

// ---------- split-bf16 MFMA GEMM: [8192 x K] @ [K x 1024] -> XL|XR ----------
// A in bf16-hi only; B in hi+lo (2 MFMA/frag): Ah*(Bh+Bl) ~ A_fp32 * B_fp32.

template <int K>
__global__ __launch_bounds__(256) void k_gemm_mfma(const unsigned short* __restrict__ Ah,
                                                   const unsigned short* __restrict__ Bh,
                                                   const unsigned short* __restrict__ Bl,
                                                   float* __restrict__ XL, float* __restrict__ XR) {
    __shared__ unsigned short sAh[4][128][8], sBh[4][128][8], sBl[4][128][8];
    int tid = threadIdx.x;
    int l = tid & 63;
    int w = tid >> 6, wm = w >> 1, wn = w & 1;
    int m0 = blockIdx.x * 128, n0 = blockIdx.y * 128;
    int lr = l & 15, kh = l >> 4;
    f32x4 acc[4][4] = {};

    for (int k0 = 0; k0 < K; k0 += 32) {
#pragma unroll
        for (int g = 0; g < 2; g++) {
            int cell = g * 256 + tid;
            int ckh = cell >> 7, cr = cell & 127;
            int ka = k0 + ckh * 8;
            gload16(Ah + (size_t)(m0 + cr) * K + ka, &sAh[ckh][cr][0]);
            gload16(Bh + (size_t)(n0 + cr) * K + ka, &sBh[ckh][cr][0]);
            gload16(Bl + (size_t)(n0 + cr) * K + ka, &sBl[ckh][cr][0]);
        }
        __syncthreads();
        short8 fah[4], fbh[4], fbl[4];
#pragma unroll
        for (int i = 0; i < 4; i++) {
            fah[i] = *(const short8*)&sAh[kh][wm * 64 + i * 16 + lr][0];
            fbh[i] = *(const short8*)&sBh[kh][wn * 64 + i * 16 + lr][0];
            fbl[i] = *(const short8*)&sBl[kh][wn * 64 + i * 16 + lr][0];
        }
#pragma unroll
        for (int i = 0; i < 4; i++)
#pragma unroll
            for (int j = 0; j < 4; j++) {
                acc[i][j] = __builtin_amdgcn_mfma_f32_16x16x32_bf16(fah[i], fbl[j], acc[i][j], 0, 0, 0);
                acc[i][j] = __builtin_amdgcn_mfma_f32_16x16x32_bf16(fah[i], fbh[j], acc[i][j], 0, 0, 0);
            }
        __syncthreads();
    }
    // C/D layout: col = lane&15, row = (lane>>4)*4 + q  [m89-verified]
    int colt = n0 + wn * 64;
    float* O = (colt < 512) ? XL : XR;
    int cb = colt & 511;
#pragma unroll
    for (int i = 0; i < 4; i++) {
        int mg = m0 + wm * 64 + i * 16 + kh * 4;
#pragma unroll
        for (int j = 0; j < 4; j++) {
            int cg = cb + j * 16 + lr;
#pragma unroll
            for (int q = 0; q < 4; q++)
                O[(size_t)(mg + q) * CH + cg] = acc[i][j][q];
        }
    }
}

// ---------- fused per-node: logits + online softmax + aggregation ----------
// 4-edge chunks: joint fold-reduce puts (edge,head) into lane bits 4:3,2:0 —
// 6 dependent shuffle steps per 4 edges (vs 10 per edge). Double-buffered
// source-row gather. Tail edges masked via logit=-1e30 (p=0).

#define LDCHUNK(cb, CS, CX)                                                    \
  {                                                                            \
    CS[0] = ssrc[(cb)];                                                        \
    CS[1] = ssrc[((cb) + 1 < end) ? (cb) + 1 : beg];                           \
    CS[2] = ssrc[((cb) + 2 < end) ? (cb) + 2 : beg];                           \
    CS[3] = ssrc[((cb) + 3 < end) ? (cb) + 3 : beg];                           \
    _Pragma("unroll") for (int e = 0; e < 4; e++) {                            \
      const float* _p = XL + (size_t)CS[e] * CH;                               \
      _Pragma("unroll") for (int r = 0; r < 8; r++) CX[e][r] = _p[r * 64 + l]; \
    }                                                                          \
  }

#define PROCESS(CX, cb)                                                        \
  {                                                                            \
    float v[4][8];                                                             \
    _Pragma("unroll") for (int e = 0; e < 4; e++)                              \
      _Pragma("unroll") for (int r = 0; r < 8; r++) {                          \
        float t = CX[e][r] + xr[r];                                            \
        t = (t > 0.f) ? t : NEG * t;                                           \
        v[e][r] = t * at[r];                                                   \
      }                                                                        \
    {                                                                          \
      int b = l & 1;                                                           \
      _Pragma("unroll") for (int e = 0; e < 4; e++) {                          \
        float k0 = b ? v[e][1] : v[e][0], s0 = b ? v[e][0] : v[e][1];          \
        float k1 = b ? v[e][3] : v[e][2], s1 = b ? v[e][2] : v[e][3];          \
        float k2 = b ? v[e][5] : v[e][4], s2 = b ? v[e][4] : v[e][5];          \
        float k3 = b ? v[e][7] : v[e][6], s3 = b ? v[e][6] : v[e][7];          \
        v[e][0] = k0 + __shfl_xor(s0, 1);                                      \
        v[e][1] = k1 + __shfl_xor(s1, 1);                                      \
        v[e][2] = k2 + __shfl_xor(s2, 1);                                      \
        v[e][3] = k3 + __shfl_xor(s3, 1);                                      \
      }                                                                        \
    }                                                                          \
    {                                                                          \
      int b = (l >> 1) & 1;                                                    \
      _Pragma("unroll") for (int e = 0; e < 4; e++) {                          \
        float k0 = b ? v[e][1] : v[e][0], s0 = b ? v[e][0] : v[e][1];          \
        float k1 = b ? v[e][3] : v[e][2], s1 = b ? v[e][2] : v[e][3];          \
        v[e][0] = k0 + __shfl_xor(s0, 2);                                      \
        v[e][1] = k1 + __shfl_xor(s1, 2);                                      \
      }                                                                        \
    }                                                                          \
    {                                                                          \
      int b = (l >> 2) & 1;                                                    \
      _Pragma("unroll") for (int e = 0; e < 4; e++) {                          \
        float k0 = b ? v[e][1] : v[e][0], s0 = b ? v[e][0] : v[e][1];          \
        v[e][0] = k0 + __shfl_xor(s0, 4);                                      \
      }                                                                        \
    }                                                                          \
    float w0, w1, z;                                                           \
    {                                                                          \
      int b = (l >> 3) & 1;                                                    \
      w0 = (b ? v[1][0] : v[0][0]) + __shfl_xor(b ? v[0][0] : v[1][0], 8);     \
      w1 = (b ? v[3][0] : v[2][0]) + __shfl_xor(b ? v[2][0] : v[3][0], 8);     \
    }                                                                          \
    {                                                                          \
      int b = (l >> 4) & 1;                                                    \
      z = (b ? w1 : w0) + __shfl_xor(b ? w0 : w1, 16);                         \
    }                                                                          \
    z += __shfl_xor(z, 32);                                                    \
    if ((cb) + ((l >> 3) & 3) >= end) z = -1e30f;                              \
    float mc = fmaxf(z, __shfl_xor(z, 8));                                     \
    mc = fmaxf(mc, __shfl_xor(mc, 16));                                        \
    unsigned long long grow = __ballot(mc > mh);                               \
    if (grow == 0ULL) {                                                        \
      float p = __expf(z - mh);                                                \
      float q = p + __shfl_xor(p, 8);                                          \
      q += __shfl_xor(q, 16);                                                  \
      sh += q;                                                                 \
      _Pragma("unroll") for (int r = 0; r < 8; r++) {                          \
        float a2 = acc[r];                                                     \
        a2 += __shfl(p, 0 * 8 + r) * CX[0][r];                                 \
        a2 += __shfl(p, 1 * 8 + r) * CX[1][r];                                 \
        a2 += __shfl(p, 2 * 8 + r) * CX[2][r];                                 \
        a2 += __shfl(p, 3 * 8 + r) * CX[3][r];                                 \
        acc[r] = a2;                                                           \
      }                                                                        \
    } else {                                                                   \
      float nm = fmaxf(mh, mc);                                                \
      float scale = __expf(mh - nm);                                           \
      float p = __expf(z - nm);                                                \
      float q = p + __shfl_xor(p, 8);                                          \
      q += __shfl_xor(q, 16);                                                  \
      sh = sh * scale + q;                                                     \
      mh = nm;                                                                 \
      _Pragma("unroll") for (int r = 0; r < 8; r++) {                          \
        float a2 = acc[r] * __shfl(scale, r);                                  \
        a2 += __shfl(p, 0 * 8 + r) * CX[0][r];                                 \
        a2 += __shfl(p, 1 * 8 + r) * CX[1][r];                                 \
        a2 += __shfl(p, 2 * 8 + r) * CX[2][r];                                 \
        a2 += __shfl(p, 3 * 8 + r) * CX[3][r];                                 \
        acc[r] = a2;                                                           \
      }                                                                        \
    }                                                                          \
  }

template <int WRITE_BF16>
__global__ __launch_bounds__(256) void k_node2(const float* __restrict__ XL,
                                               const float* __restrict__ XR,
                                               const int* __restrict__ rowptr,
                                               const int* __restrict__ ssrc,
                                               const float* __restrict__ att,
                                               const float* __restrict__ bias,
                                               float* __restrict__ OUT,
                                               unsigned short* __restrict__ OAh) {
    int n = blockIdx.x * 4 + (threadIdx.x >> 6);
    int l = threadIdx.x & 63;
    int beg = rowptr[n], end = rowptr[n + 1];

    float xr[8], at[8], acc[8];
    const float* pr = XR + (size_t)n * CH;
#pragma unroll
    for (int r = 0; r < 8; r++) {
        xr[r] = pr[r * 64 + l];
        at[r] = att[r * 64 + l];
        acc[r] = 0.f;
    }
    float mh = -1e30f, sh = 0.f;

    int srcA[4], srcB[4];
    float curA[4][8], curB[4][8];
    LDCHUNK(beg, srcA, curA);
    int base = beg;
    while (true) {
        if (base + 4 < end) LDCHUNK(base + 4, srcB, curB);
        PROCESS(curA, base);
        base += 4;
        if (base >= end) break;
        if (base + 4 < end) LDCHUNK(base + 4, srcA, curA);
        PROCESS(curB, base);
        base += 4;
        if (base >= end) break;
    }

    float inv = 1.f / sh;
    size_t obase = (size_t)n * CH;
#pragma unroll
    for (int r = 0; r < 8; r++) {
        float wv = acc[r] * __shfl(inv, r) + bias[r * 64 + l];
        if (WRITE_BF16) {
            OAh[obase + r * 64 + l] = bf16rne(wv);
        } else {
            wv = (wv > 0.f) ? wv : (__expf(wv) - 1.f);
            OUT[obase + r * 64 + l] = wv;
        }
    }
}

// ---------- host ----------

extern "C" void kernel_launch(void* const* d_in, const int* in_sizes, int n_in,
                              void* d_out, int out_size, void* d_ws, size_t ws_size,
                              hipStream_t stream) {
    const float* x    = (const float*)d_in[0];
    const int*   ei   = (const int*)d_in[1];
    const float* W1l  = (const float*)d_in[2];
    const float* W1r  = (const float*)d_in[3];
    const float* att1 = (const float*)d_in[4];
    const float* b1   = (const float*)d_in[5];
    const float* W2l  = (const float*)d_in[6];
    const float* W2r  = (const float*)d_in[7];
    const float* att2 = (const float*)d_in[8];
    const float* b2   = (const float*)d_in[9];
    float* out = (float*)d_out;

    char* ws = (char*)d_ws;
    int* rowptr = (int*)ws;                 // NN+1
    int* cursor = rowptr + NN + 1;          // NN
    int* deg    = cursor + NN;              // NN
    int* ssrc   = deg + NN;                 // EPAD
    float* XL = (float*)(((uintptr_t)(ssrc + EPAD) + 255) & ~(uintptr_t)255);
    float* XR = XL + (size_t)NN * CH;
    unsigned short* A_h = (unsigned short*)(XR + (size_t)NN * CH);  // NN*CH bf16
    unsigned short* W1h = A_h + (size_t)NN * CH;   // 1024*FIN
    unsigned short* W1o = W1h + 1024 * FIN;
    unsigned short* W2h = W1o + 1024 * FIN;        // 1024*CH
    unsigned short* W2o = W2h + 1024 * CH;

    hipMemsetAsync(cursor, 0, (size_t)2 * NN * sizeof(int), stream);
    k_deg<<<(EPAD + 255) / 256, 256, 0, stream>>>(ei, deg);
    k_scan<<<1, 1024, 0, stream>>>(deg, rowptr);
    k_scatter<<<(EPAD + 255) / 256, 256, 0, stream>>>(ei, rowptr, cursor, ssrc);
    k_cvt_w<FIN><<<1024 * FIN / 256, 256, 0, stream>>>(W1l, W1r, W1h, W1o);
    k_cvt_w<CH><<<1024 * CH / 256, 256, 0, stream>>>(W2l, W2r, W2h, W2o);

    for (int b = 0; b < 2; b++) {
        const float* f = x + (size_t)b * NN * FIN;
        k_cvt_ah<<<NN * FIN / 4 / 256, 256, 0, stream>>>(f, A_h, NN * FIN / 4);
        k_gemm_mfma<FIN><<<dim3(NN / 128, 8), 256, 0, stream>>>(A_h, W1h, W1o, XL, XR);
        k_node2<1><<<NN / 4, 256, 0, stream>>>(XL, XR, rowptr, ssrc, att1, b1, nullptr, A_h);
        k_gemm_mfma<CH><<<dim3(NN / 128, 8), 256, 0, stream>>>(A_h, W2h, W2o, XL, XR);
        k_node2<0><<<NN / 4, 256, 0, stream>>>(XL, XR, rowptr, ssrc, att2, b2,
                                               out + (size_t)b * NN * CH, nullptr);
    }
}

// Round 5
// 351.457 us; speedup vs baseline: 2.7504x; 1.1550x over previous
//
#include <hip/hip_runtime.h>
#include <cstdint>

#define NN 8192
#define EE 131072
#define EPAD (EE + NN)   // edges + self loops = 139264
#define FIN 128
#define CH 512           // H*HID = H*OUT
#define NH 8
#define NEG 0.2f

typedef __attribute__((ext_vector_type(8))) short short8;
typedef __attribute__((ext_vector_type(4))) float f32x4;

__device__ inline unsigned short bf16rne(float x) {
    unsigned u = __float_as_uint(x);
    unsigned r = (u + 0x7FFFu + ((u >> 16) & 1u)) >> 16;
    return (unsigned short)r;
}
__device__ inline float bf16tof(unsigned short h) {
    return __uint_as_float((unsigned)h << 16);
}
__device__ inline void gload16(const void* g, void* l) {
    __builtin_amdgcn_global_load_lds((const __attribute__((address_space(1))) void*)g,
                                     (__attribute__((address_space(3))) void*)l, 16, 0, 0);
}

// ---------- CSR build ----------

__global__ __launch_bounds__(256) void k_deg(const int* __restrict__ ei, int* __restrict__ deg) {
    int e = blockIdx.x * 256 + threadIdx.x;
    if (e >= EPAD) return;
    int dst = (e < EE) ? ei[EE + e] : (e - EE);
    atomicAdd(&deg[dst], 1);
}

__global__ __launch_bounds__(1024) void k_scan(const int* __restrict__ deg, int* __restrict__ rowptr) {
    __shared__ int part[1024];
    int t = threadIdx.x;
    int loc[8];
    int s = 0;
#pragma unroll
    for (int i = 0; i < 8; i++) { loc[i] = s; s += deg[t * 8 + i]; }
    part[t] = s;
    __syncthreads();
    if (t == 0) {
        int run = 0;
        for (int i = 0; i < 1024; i++) { int tmp = part[i]; part[i] = run; run += tmp; }
        rowptr[NN] = run;
    }
    __syncthreads();
    int base = part[t];
#pragma unroll
    for (int i = 0; i < 8; i++) rowptr[t * 8 + i] = base + loc[i];
}

__global__ __launch_bounds__(256) void k_scatter(const int* __restrict__ ei, const int* __restrict__ rowptr,
                                                 int* __restrict__ cursor, int* __restrict__ ssrc) {
    int e = blockIdx.x * 256 + threadIdx.x;
    if (e >= EPAD) return;
    int src = (e < EE) ? ei[e] : (e - EE);
    int dst = (e < EE) ? ei[EE + e] : (e - EE);
    int pos = rowptr[dst] + atomicAdd(&cursor[dst], 1);
    ssrc[pos] = src;
}

// ---------- conversions ----------

__global__ __launch_bounds__(256) void k_cvt_ah(const float* __restrict__ F,
                                                unsigned short* __restrict__ Ah, int n4) {
    int i = blockIdx.x * 256 + threadIdx.x;
    if (i >= n4) return;
    f32x4 v = ((const f32x4*)F)[i];
#pragma unroll
    for (int c = 0; c < 4; c++) Ah[i * 4 + c] = bf16rne(v[c]);
}

// W[K][512] (Wl,Wr) -> Wt[n=1024][K] hi/lo (transposed, K contiguous)
template <int K>
__global__ __launch_bounds__(256) void k_cvt_w(const float* __restrict__ Wl, const float* __restrict__ Wr,
                                               unsigned short* __restrict__ Wh, unsigned short* __restrict__ Wlo) {
    int idx = blockIdx.x * 256 + threadIdx.x;   // = n*K + k
    int n = idx / K, k = idx % K;
    const float* W = (n < 512) ? Wl : Wr;
    float x = W[k * 512 + (n & 511)];
    unsigned short h = bf16rne(x);
    Wh[idx] = h;
    Wlo[idx] = bf16rne(x - bf16tof(h));
}

// ---------- split-bf16 MFMA GEMM: [8192 x K] @ [K x 1024] -> XL|XR ----------
// A in bf16-hi only; B in hi+lo (2 MFMA/frag): Ah*(Bh+Bl) ~ A_fp32 * B_fp32.

template <int K>
__global__ __launch_bounds__(256) void k_gemm_mfma(const unsigned short* __restrict__ Ah,
                                                   const unsigned short* __restrict__ Bh,
                                                   const unsigned short* __restrict__ Bl,
                                                   float* __restrict__ XL, float* __restrict__ XR) {
    __shared__ unsigned short sAh[4][128][8], sBh[4][128][8], sBl[4][128][8];
    int tid = threadIdx.x;
    int l = tid & 63;
    int w = tid >> 6, wm = w >> 1, wn = w & 1;
    int m0 = blockIdx.x * 128, n0 = blockIdx.y * 128;
    int lr = l & 15, kh = l >> 4;
    f32x4 acc[4][4] = {};

    for (int k0 = 0; k0 < K; k0 += 32) {
#pragma unroll
        for (int g = 0; g < 2; g++) {
            int cell = g * 256 + tid;
            int ckh = cell >> 7, cr = cell & 127;
            int ka = k0 + ckh * 8;
            gload16(Ah + (size_t)(m0 + cr) * K + ka, &sAh[ckh][cr][0]);
            gload16(Bh + (size_t)(n0 + cr) * K + ka, &sBh[ckh][cr][0]);
            gload16(Bl + (size_t)(n0 + cr) * K + ka, &sBl[ckh][cr][0]);
        }
        __syncthreads();
        short8 fah[4], fbh[4], fbl[4];
#pragma unroll
        for (int i = 0; i < 4; i++) {
            fah[i] = *(const short8*)&sAh[kh][wm * 64 + i * 16 + lr][0];
            fbh[i] = *(const short8*)&sBh[kh][wn * 64 + i * 16 + lr][0];
            fbl[i] = *(const short8*)&sBl[kh][wn * 64 + i * 16 + lr][0];
        }
#pragma unroll
        for (int i = 0; i < 4; i++)
#pragma unroll
            for (int j = 0; j < 4; j++) {
                acc[i][j] = __builtin_amdgcn_mfma_f32_16x16x32_bf16(fah[i], fbl[j], acc[i][j], 0, 0, 0);
                acc[i][j] = __builtin_amdgcn_mfma_f32_16x16x32_bf16(fah[i], fbh[j], acc[i][j], 0, 0, 0);
            }
        __syncthreads();
    }
    // C/D layout: col = lane&15, row = (lane>>4)*4 + q  [m89-verified]
    int colt = n0 + wn * 64;
    float* O = (colt < 512) ? XL : XR;
    int cb = colt & 511;
#pragma unroll
    for (int i = 0; i < 4; i++) {
        int mg = m0 + wm * 64 + i * 16 + kh * 4;
#pragma unroll
        for (int j = 0; j < 4; j++) {
            int cg = cb + j * 16 + lr;
#pragma unroll
            for (int q = 0; q < 4; q++)
                O[(size_t)(mg + q) * CH + cg] = acc[i][j][q];
        }
    }
}

// ---------- fused per-node: logits + online softmax + aggregation ----------
// 2 waves per node (head-groups of 4). Per edge each lane gathers 4 floats.
// 2-edge chunks, double-buffered. 6 dependent shuffle levels fold
// (head2bits, edge1bit) into lane bits 3:0 then xor 8/16/32 sums channels.
// Tail edges masked via logit=-1e30 (p=0).

#define LDCHUNK(cb, CS, CX)                                                    \
  {                                                                            \
    CS[0] = ssrc[(cb)];                                                        \
    CS[1] = ssrc[((cb) + 1 < end) ? (cb) + 1 : beg];                           \
    _Pragma("unroll") for (int e = 0; e < 2; e++) {                            \
      const float* _p = XLg + (size_t)CS[e] * CH;                              \
      _Pragma("unroll") for (int r = 0; r < 4; r++) CX[e][r] = _p[r * 64];     \
    }                                                                          \
  }

#define PROCESS(CX, cb)                                                        \
  {                                                                            \
    float v[2][4];                                                             \
    _Pragma("unroll") for (int e = 0; e < 2; e++)                              \
      _Pragma("unroll") for (int r = 0; r < 4; r++) {                          \
        float t = CX[e][r] + xr[r];                                            \
        t = (t > 0.f) ? t : NEG * t;                                           \
        v[e][r] = t * at[r];                                                   \
      }                                                                        \
    {                                                                          \
      int b = l & 1;                                                           \
      _Pragma("unroll") for (int e = 0; e < 2; e++) {                          \
        float k0 = b ? v[e][1] : v[e][0], s0 = b ? v[e][0] : v[e][1];          \
        float k1 = b ? v[e][3] : v[e][2], s1 = b ? v[e][2] : v[e][3];          \
        v[e][0] = k0 + __shfl_xor(s0, 1);                                      \
        v[e][1] = k1 + __shfl_xor(s1, 1);                                      \
      }                                                                        \
    }                                                                          \
    {                                                                          \
      int b = (l >> 1) & 1;                                                    \
      _Pragma("unroll") for (int e = 0; e < 2; e++) {                          \
        float k0 = b ? v[e][1] : v[e][0], s0 = b ? v[e][0] : v[e][1];          \
        v[e][0] = k0 + __shfl_xor(s0, 2);                                      \
      }                                                                        \
    }                                                                          \
    float z;                                                                   \
    {                                                                          \
      int b = (l >> 2) & 1;                                                    \
      z = (b ? v[1][0] : v[0][0]) + __shfl_xor(b ? v[0][0] : v[1][0], 4);      \
    }                                                                          \
    z += __shfl_xor(z, 8);                                                     \
    z += __shfl_xor(z, 16);                                                    \
    z += __shfl_xor(z, 32);                                                    \
    if ((cb) + ((l >> 2) & 1) >= end) z = -1e30f;                              \
    float mc = fmaxf(z, __shfl_xor(z, 4));                                     \
    unsigned long long grow = __ballot(mc > mh);                               \
    if (grow == 0ULL) {                                                        \
      float p = __expf(z - mh);                                                \
      float q = p + __shfl_xor(p, 4);                                          \
      sh += q;                                                                 \
      _Pragma("unroll") for (int r = 0; r < 4; r++)                            \
        acc[r] += __shfl(p, r) * CX[0][r] + __shfl(p, 4 + r) * CX[1][r];       \
    } else {                                                                   \
      float nm = fmaxf(mh, mc);                                                \
      float scale = __expf(mh - nm);                                           \
      float p = __expf(z - nm);                                                \
      float q = p + __shfl_xor(p, 4);                                          \
      sh = sh * scale + q;                                                     \
      mh = nm;                                                                 \
      _Pragma("unroll") for (int r = 0; r < 4; r++)                            \
        acc[r] = acc[r] * __shfl(scale, r) +                                   \
                 __shfl(p, r) * CX[0][r] + __shfl(p, 4 + r) * CX[1][r];        \
    }                                                                          \
  }

template <int WRITE_BF16>
__global__ __launch_bounds__(256) void k_node2(const float* __restrict__ XL,
                                               const float* __restrict__ XR,
                                               const int* __restrict__ rowptr,
                                               const int* __restrict__ ssrc,
                                               const float* __restrict__ att,
                                               const float* __restrict__ bias,
                                               float* __restrict__ OUT,
                                               unsigned short* __restrict__ OAh) {
    int w = threadIdx.x >> 6;
    int n = blockIdx.x * 2 + (w >> 1);
    int g = w & 1;                       // head-group: heads g*4 .. g*4+3
    int l = threadIdx.x & 63;
    int beg = rowptr[n], end = rowptr[n + 1];
    int hb = g * 256 + l;                // channel base within row

    const float* XLg = XL + hb;
    float xr[4], at[4], acc[4];
    const float* pr = XR + (size_t)n * CH + hb;
#pragma unroll
    for (int r = 0; r < 4; r++) {
        xr[r] = pr[r * 64];
        at[r] = att[hb + r * 64];
        acc[r] = 0.f;
    }
    float mh = -1e30f, sh = 0.f;

    int srcA[2], srcB[2];
    float curA[2][4], curB[2][4];
    LDCHUNK(beg, srcA, curA);
    int base = beg;
    while (true) {
        if (base + 2 < end) LDCHUNK(base + 2, srcB, curB);
        PROCESS(curA, base);
        base += 2;
        if (base >= end) break;
        if (base + 2 < end) LDCHUNK(base + 2, srcA, curA);
        PROCESS(curB, base);
        base += 2;
        if (base >= end) break;
    }

    float inv = 1.f / sh;
    size_t obase = (size_t)n * CH + hb;
#pragma unroll
    for (int r = 0; r < 4; r++) {
        float wv = acc[r] * __shfl(inv, r) + bias[hb + r * 64];
        if (WRITE_BF16) {
            OAh[obase + r * 64] = bf16rne(wv);
        } else {
            wv = (wv > 0.f) ? wv : (__expf(wv) - 1.f);
            OUT[obase + r * 64] = wv;
        }
    }
}

// ---------- host ----------

extern "C" void kernel_launch(void* const* d_in, const int* in_sizes, int n_in,
                              void* d_out, int out_size, void* d_ws, size_t ws_size,
                              hipStream_t stream) {
    const float* x    = (const float*)d_in[0];
    const int*   ei   = (const int*)d_in[1];
    const float* W1l  = (const float*)d_in[2];
    const float* W1r  = (const float*)d_in[3];
    const float* att1 = (const float*)d_in[4];
    const float* b1   = (const float*)d_in[5];
    const float* W2l  = (const float*)d_in[6];
    const float* W2r  = (const float*)d_in[7];
    const float* att2 = (const float*)d_in[8];
    const float* b2   = (const float*)d_in[9];
    float* out = (float*)d_out;

    char* ws = (char*)d_ws;
    int* rowptr = (int*)ws;                 // NN+1
    int* cursor = rowptr + NN + 1;          // NN
    int* deg    = cursor + NN;              // NN
    int* ssrc   = deg + NN;                 // EPAD
    float* XL = (float*)(((uintptr_t)(ssrc + EPAD) + 255) & ~(uintptr_t)255);
    float* XR = XL + (size_t)NN * CH;
    unsigned short* A_h = (unsigned short*)(XR + (size_t)NN * CH);  // NN*CH bf16
    unsigned short* W1h = A_h + (size_t)NN * CH;   // 1024*FIN
    unsigned short* W1o = W1h + 1024 * FIN;
    unsigned short* W2h = W1o + 1024 * FIN;        // 1024*CH
    unsigned short* W2o = W2h + 1024 * CH;

    hipMemsetAsync(cursor, 0, (size_t)2 * NN * sizeof(int), stream);
    k_deg<<<(EPAD + 255) / 256, 256, 0, stream>>>(ei, deg);
    k_scan<<<1, 1024, 0, stream>>>(deg, rowptr);
    k_scatter<<<(EPAD + 255) / 256, 256, 0, stream>>>(ei, rowptr, cursor, ssrc);
    k_cvt_w<FIN><<<1024 * FIN / 256, 256, 0, stream>>>(W1l, W1r, W1h, W1o);
    k_cvt_w<CH><<<1024 * CH / 256, 256, 0, stream>>>(W2l, W2r, W2h, W2o);

    for (int b = 0; b < 2; b++) {
        const float* f = x + (size_t)b * NN * FIN;
        k_cvt_ah<<<NN * FIN / 4 / 256, 256, 0, stream>>>(f, A_h, NN * FIN / 4);
        k_gemm_mfma<FIN><<<dim3(NN / 128, 8), 256, 0, stream>>>(A_h, W1h, W1o, XL, XR);
        k_node2<1><<<NN / 2, 256, 0, stream>>>(XL, XR, rowptr, ssrc, att1, b1, nullptr, A_h);
        k_gemm_mfma<CH><<<dim3(NN / 128, 8), 256, 0, stream>>>(A_h, W2h, W2o, XL, XR);
        k_node2<0><<<NN / 2, 256, 0, stream>>>(XL, XR, rowptr, ssrc, att2, b2,
                                               out + (size_t)b * NN * CH, nullptr);
    }
}